// Round 9
// baseline (87.610 us; speedup 1.0000x reference)
//
#include <hip/hip_runtime.h>
#include <hip/hip_bf16.h>

// CFAR via summed-area table — R15: R13 (proven passing) + chunked XCD
// blockIdx swizzle on final ONLY. R14's SP hoisting reverted (failed
// correctness despite index-exact analysis — not kept un-understood).
//   sat     : per 4-row segment (1024 blocks): 4 waves compute row prefixes
//             P[0..3] in LDS; one barrier; column-accumulate quad-cols and
//             write segment-local SAT Q (float4). [R13-proven]
//   segscan : SP[img][s][c] = exclusive prefix over segments of Q's segment-
//             last rows. [R13-proven]
//   final   : stage Qg rows (Q + SP fold) for hi1/lo1 then hi3/lo3 through
//             32 KB LDS; SAT window math. [R13-proven body; swizzled blockIdx]
// BG_AREA = 321^2-161^2 = 77120 ; FRONT_DIV = 161^2*1.8 = 46657.8

#define IMG 4
#define H 1024
#define W 1024
#define SEGR 4
#define NSEG 256                   // H / SEGR

// ------- Kernel 1: row prefix + segment-local column prefix (SAT) ----------
__global__ __launch_bounds__(256) void sat_kernel(const float* __restrict__ x,
                                                  float* __restrict__ Q) {
    __shared__ float P[4][W];        // 16384 B — per-wave row prefix
    const int wave = threadIdx.x >> 6;
    const int lane = threadIdx.x & 63;
    const int tid  = threadIdx.x;
    const size_t rowbase = (size_t)blockIdx.x << 2;   // flat rows over images

    // ---- phase 1: row prefix into LDS (per wave, own row)
    {
        const float4* xr = reinterpret_cast<const float4*>(x + (rowbase + wave) * W);
        float v[16];
        float4 a0 = xr[(lane << 2) + 0];
        float4 a1 = xr[(lane << 2) + 1];
        float4 a2 = xr[(lane << 2) + 2];
        float4 a3 = xr[(lane << 2) + 3];
        v[0]=a0.x; v[1]=a0.y; v[2]=a0.z; v[3]=a0.w;
        v[4]=a1.x; v[5]=a1.y; v[6]=a1.z; v[7]=a1.w;
        v[8]=a2.x; v[9]=a2.y; v[10]=a2.z; v[11]=a2.w;
        v[12]=a3.x; v[13]=a3.y; v[14]=a3.z; v[15]=a3.w;
        float s = 0.f;
#pragma unroll
        for (int j = 0; j < 16; ++j) { s += v[j]; v[j] = s; }
        float t = s;
#pragma unroll
        for (int d = 1; d < 64; d <<= 1) {
            float u = __shfl_up(t, d, 64);
            if (lane >= d) t += u;
        }
        const float off = t - s;        // exclusive prefix of lane totals
#pragma unroll
        for (int j = 0; j < 16; ++j) v[j] += off;

        float4* Pr = reinterpret_cast<float4*>(P[wave]);
        Pr[(lane << 2) + 0] = make_float4(v[0], v[1], v[2], v[3]);
        Pr[(lane << 2) + 1] = make_float4(v[4], v[5], v[6], v[7]);
        Pr[(lane << 2) + 2] = make_float4(v[8], v[9], v[10], v[11]);
        Pr[(lane << 2) + 3] = make_float4(v[12], v[13], v[14], v[15]);
    }
    __syncthreads();   // the only barrier

    // ---- phase 2: column prefix over the 4 rows; float4 LDS reads + stores
    float4 acc = make_float4(0.f, 0.f, 0.f, 0.f);
    float4* Qo = reinterpret_cast<float4*>(Q) + (rowbase << 8) + tid;
#pragma unroll
    for (int rr = 0; rr < SEGR; ++rr) {
        const float4 h = reinterpret_cast<const float4*>(P[rr])[tid];
        acc.x += h.x; acc.y += h.y; acc.z += h.z; acc.w += h.w;
        Qo[(size_t)rr << 8] = acc;
    }
}

// ------- Kernel 2: exclusive scan of segment totals per column -------------
// Seg total of seg t = Q row (4t+3). Block = (img, 64-col group); wave w owns
// segs 64w..64w+63 in registers (coalesced 256 B loads), in-lane exclusive
// scan, cross-wave fixup via LDS. 64 blocks x 256.
__global__ __launch_bounds__(256) void segscan_kernel(const float* __restrict__ Q,
                                                      float* __restrict__ SP) {
    __shared__ float T[4][64];
    const int wave = threadIdx.x >> 6;
    const int lane = threadIdx.x & 63;
    const int img  = blockIdx.x >> 4;                    // 0..3
    const int col  = ((blockIdx.x & 15) << 6) + lane;    // 0..1023

    const float* Qi = Q + ((size_t)img << 20);
    float v[64];
#pragma unroll
    for (int s = 0; s < 64; ++s) {
        const int seg = (wave << 6) + s;
        v[s] = Qi[((size_t)((seg << 2) + 3) << 10) + col];
    }
    float run = 0.f;
#pragma unroll
    for (int s = 0; s < 64; ++s) { const float t = v[s]; v[s] = run; run += t; }
    T[wave][lane] = run;
    __syncthreads();
    float off = 0.f;
    for (int w = 0; w < wave; ++w) off += T[w][lane];    // wave-uniform trip
    float* SPo = SP + ((size_t)img << 18) + col;
#pragma unroll
    for (int s = 0; s < 64; ++s)
        SPo[(size_t)(((wave << 6) + s)) << 10] = v[s] + off;
}

// ------- Kernel 3: final — SAT window diffs ---------------------------------
// Block = (img, 4-row group) after chunked XCD swizzle; 256 threads, 32 KB
// LDS. Two stage+math passes [R13-proven body]: pass A stages Qg rows
// {r0+80+i, r0-81+i} (SP folded; neg rows = 0), computes front; pass B
// stages {r0+160+i, r0-161+i}, computes allsum and out.
__global__ __launch_bounds__(256) void final_kernel(const float* __restrict__ Q,
                                                    const float* __restrict__ SP,
                                                    float* __restrict__ out) {
    __shared__ float S[8][W];        // 32768 B
    const int tid = threadIdx.x;
    // chunked XCD swizzle: 1024 blocks = 8 XCDs x 128-chunk (bijective)
    const int lb  = ((blockIdx.x & 7) << 7) + (blockIdx.x >> 3);
    const int img = lb >> 8;
    const int r0  = (lb & 255) << 2;

    const float4* Q4  = reinterpret_cast<const float4*>(Q)  + ((size_t)img << 18);
    const float4* SP4 = reinterpret_cast<const float4*>(SP) + ((size_t)img << 16);
    float4* S4 = reinterpret_cast<float4*>(&S[0][0]);

    // ---- pass A: stage hi1 rows (slots 0..3) and lo1 rows (slots 4..7)
#pragma unroll
    for (int i = 0; i < 4; ++i) {
        {   // hi1 = min(r0+80+i, 1023)  (always >= 0)
            const int row = min(r0 + 80 + i, H - 1);
            const float4 a = Q4[((size_t)row << 8) + tid];
            const float4 b = SP4[((size_t)(row >> 2) << 8) + tid];
            S4[(i << 8) + tid] = make_float4(a.x + b.x, a.y + b.y, a.z + b.z, a.w + b.w);
        }
        {   // lo1 = r0-81+i  (may be negative -> zeros)
            const int row = r0 - 81 + i;
            float4 vv = make_float4(0.f, 0.f, 0.f, 0.f);
            if (row >= 0) {
                const float4 a = Q4[((size_t)row << 8) + tid];
                const float4 b = SP4[((size_t)(row >> 2) << 8) + tid];
                vv = make_float4(a.x + b.x, a.y + b.y, a.z + b.z, a.w + b.w);
            }
            S4[((4 + i) << 8) + tid] = vv;
        }
    }
    __syncthreads();

    float fr[4][4];
#pragma unroll
    for (int i = 0; i < 4; ++i) {
#pragma unroll
        for (int j = 0; j < 4; ++j) {
            const int c  = tid + (j << 8);
            const int kp = min(c + 80, W - 1);
            const int km = c - 81;
            const float m = (km >= 0) ? 1.f : 0.f;
            const int k  = max(km, 0);
            fr[i][j] = (S[i][kp] - m * S[i][k]) - (S[4 + i][kp] - m * S[4 + i][k]);
        }
    }
    __syncthreads();   // before overwriting S

    // ---- pass B: stage hi3 rows (slots 0..3) and lo3 rows (slots 4..7)
#pragma unroll
    for (int i = 0; i < 4; ++i) {
        {   // hi3 = min(r0+160+i, 1023)
            const int row = min(r0 + 160 + i, H - 1);
            const float4 a = Q4[((size_t)row << 8) + tid];
            const float4 b = SP4[((size_t)(row >> 2) << 8) + tid];
            S4[(i << 8) + tid] = make_float4(a.x + b.x, a.y + b.y, a.z + b.z, a.w + b.w);
        }
        {   // lo3 = r0-161+i
            const int row = r0 - 161 + i;
            float4 vv = make_float4(0.f, 0.f, 0.f, 0.f);
            if (row >= 0) {
                const float4 a = Q4[((size_t)row << 8) + tid];
                const float4 b = SP4[((size_t)(row >> 2) << 8) + tid];
                vv = make_float4(a.x + b.x, a.y + b.y, a.z + b.z, a.w + b.w);
            }
            S4[((4 + i) << 8) + tid] = vv;
        }
    }
    __syncthreads();

    const float SCALE = (float)(77120.0 / 46657.8);   // BG_AREA / FRONT_DIV
    float* o = out + ((size_t)img << 20);
#pragma unroll
    for (int i = 0; i < 4; ++i) {
        const int r = r0 + i;
#pragma unroll
        for (int j = 0; j < 4; ++j) {
            const int c  = tid + (j << 8);
            const int kp = min(c + 160, W - 1);
            const int km = c - 161;
            const float m = (km >= 0) ? 1.f : 0.f;
            const int k  = max(km, 0);
            const float allsum = (S[i][kp] - m * S[i][k]) - (S[4 + i][kp] - m * S[4 + i][k]);
            const float front  = fr[i][j];
            o[((size_t)r << 10) + c] = SCALE * front * __builtin_amdgcn_rcpf(allsum - front);
        }
    }
}

extern "C" void kernel_launch(void* const* d_in, const int* in_sizes, int n_in,
                              void* d_out, int out_size, void* d_ws, size_t ws_size,
                              hipStream_t stream) {
    const float* x = (const float*)d_in[0];
    float* outp = (float*)d_out;
    float* Q   = (float*)d_ws;                           // 16 MB (SAT, seg-local)
    float* SPb = Q + (size_t)IMG * H * W;                // 4 MB (IMG*NSEG*W fp32)

    sat_kernel<<<dim3(IMG * NSEG), dim3(256), 0, stream>>>(x, Q);
    segscan_kernel<<<dim3(64), dim3(256), 0, stream>>>(Q, SPb);
    final_kernel<<<dim3(IMG * (H / 4)), dim3(256), 0, stream>>>(Q, SPb, outp);
}